// Round 10
// baseline (100.635 us; speedup 1.0000x reference)
//
#include <hip/hip_runtime.h>
#include <math.h>

typedef float f32x4 __attribute__((ext_vector_type(4)));
typedef __attribute__((address_space(3))) unsigned int lds_u32;
typedef __attribute__((address_space(1))) const unsigned int glb_u32;

// ---------------------------------------------------------------------------
// R30: TRIANGULAR pass1 with write-once partial slots (no atomics anywhere).
//
// Evidence trail: pass1 is ~37-45us across FIVE structures spanning 2-6
// blocks/CU, with/without barriers-per-phase, branch-free or not, while
// issue arithmetic says ~15us and R0 counters showed ~70% idle with no
// dominant stall counter. Occupancy is falsified as the bottleneck (R24:4/CU
// = R28:6/CU = flat; prior session: anti-correlated). Remaining hypothesis:
// the cost scales with the WORK itself. Triangular halves the work: MFMA
// 8.6->4.3us, exp 67M->34M, staging 128->66MB.
//
// Write-once slot scheme (composes R0's symmetry with R23's no-atomics):
// block (bi,bj), bi<=bj, writes row-partials of panel bi to slot bj and
// col-partials of panel bj to slot bi of P/Q[64][N]. Every (slot c, row i
// in panel p) has EXACTLY one writer: c>p -> block (p,c) row-side; c<p ->
// block (c,p) col-side; c==p -> diag block row-side. finalize folds 64.
//
// Also: whole 16KB B-panel staged up-front -> only TWO barriers per block
// (vs 8 phase barriers), one fat 64-MFMA compute region. A-fragments via
// 8 one-time swizzled global gathers (R28-proven). exp2 scale-folding kept.
// ---------------------------------------------------------------------------

// Kernel 1: row normalization -> fp8 e4m3 rows PRE-SWIZZLED (16B chunk c of
// row r stored at chunk c ^ (r&7)). Zeroes out[0].
__global__ __launch_bounds__(256) void norm_kernel(
    const float* __restrict__ X, unsigned char* __restrict__ Y8,
    float* __restrict__ out, float scaleAB) {
  int t = threadIdx.x;
  int row = blockIdx.x * 8 + (t >> 5);
  int l32 = t & 31;
  float4 v = ((const float4*)(X + (size_t)row * 128))[l32];
  float s = v.x * v.x + v.y * v.y + v.z * v.z + v.w * v.w;
  s += __shfl_xor(s, 1);
  s += __shfl_xor(s, 2);
  s += __shfl_xor(s, 4);
  s += __shfl_xor(s, 8);
  s += __shfl_xor(s, 16);
  float inv = scaleAB * rsqrtf(fmaxf(s, 1e-24f));
  int pk = __builtin_amdgcn_cvt_pk_fp8_f32(v.x * inv, v.y * inv, 0, false);
  pk = __builtin_amdgcn_cvt_pk_fp8_f32(v.z * inv, v.w * inv, pk, true);
  int chunk = l32 >> 2;
  int off = ((chunk ^ (row & 7)) << 4) + ((l32 & 3) << 2);
  *(unsigned int*)(Y8 + (size_t)row * 128 + off) = (unsigned)pk;
  if (blockIdx.x == 0 && t == 0) out[0] = 0.f;
}

// ---------------------------------------------------------------------------
// Kernel 2: triangular similarity pass. 2080 blocks (64x65/2 tile pairs),
// 256 thr = 4 waves; wave w owns rows [w*32,+32) of panel bi x all 128 cols
// of panel bj, in 2 col-phases of 64 (both staged up-front).
__global__ __launch_bounds__(256, 4) void pass1_kernel(
    const unsigned char* __restrict__ Y8, const int* __restrict__ lab,
    float* __restrict__ P, float* __restrict__ Q, float* __restrict__ S,
    int nt, int N) {
  __shared__ unsigned char Bs[2][64][128];  // = 16KB: rows [j0, j0+128)
  __shared__ float tcolS[128], pcolS[128];
  __shared__ float sS[4];

  // decode linear block id -> (bi, bj), bi <= bj (R0-proven)
  int b = blockIdx.x;
  float ntf = (float)nt;
  int bi = (int)((2.f * ntf + 1.f -
                  sqrtf((2.f * ntf + 1.f) * (2.f * ntf + 1.f) - 8.f * (float)b)) *
                 0.5f);
  if (bi < 0) bi = 0;
  while ((bi + 1) * nt - ((bi + 1) * bi) / 2 <= b) ++bi;
  while (bi * nt - (bi * (bi - 1)) / 2 > b) --bi;
  int bj = bi + (b - (bi * nt - (bi * (bi - 1)) / 2));
  const int i0 = bi * 128, j0 = bj * 128;
  const bool offdiag = (bi != bj);

  const int t = threadIdx.x;
  const int w = t >> 6, lane = t & 63;
  const int quad = lane >> 4, l16 = lane & 15;
  const int rbase = w * 32;  // wave owns rows [rbase, rbase+32)
  const int sw = l16 & 7;

  // ---- stage whole B panel (16KB = 1024 chunks; 4 segs per wave) ----
#pragma unroll
  for (int k = 0; k < 4; ++k) {
    const int c0 = w * 64 + k * 256;  // wave-uniform 16B-chunk index
    const int cc = c0 + lane;
    __builtin_amdgcn_global_load_lds(
        (glb_u32*)(Y8 + (size_t)j0 * 128 + (size_t)cc * 16),
        (lds_u32*)((unsigned char*)&Bs[0][0][0] + c0 * 16), 16, 0, 0);
  }

  // ---- A fragments: one-time swizzled gathers -> registers (L2-hot) ----
  long af[4][2];
#pragma unroll
  for (int ks = 0; ks < 4; ++ks) {
    const int ch = ks * 2 + (quad >> 1);
    const int off = ((ch ^ sw) << 4) + ((quad & 1) << 3);
#pragma unroll
    for (int p = 0; p < 2; ++p)
      af[ks][p] =
          *(const long*)(Y8 + (size_t)(i0 + rbase + p * 16 + l16) * 128 + off);
  }
  int lr[2][4];
#pragma unroll
  for (int pi = 0; pi < 2; ++pi)
#pragma unroll
    for (int r = 0; r < 4; ++r)
      lr[pi][r] = lab[i0 + rbase + pi * 16 + quad * 4 + r];

  if (t < 128) tcolS[t] = 0.f;
  else pcolS[t - 128] = 0.f;

  float trow[2][4] = {};  // row exp-sums (self excluded on diag)
  float pr[2][4] = {};    // row positive exp-sums
  float sacc = 0.f;       // sum of s*log2e over positives (single-counted)

  __syncthreads();  // B staged (vmcnt drained) + LDS init visible

  // ==== 2 col-phases of 64, straight-line (no barriers inside) ====
#pragma unroll
  for (int jp = 0; jp < 2; ++jp) {
    const int jb = jp * 64;

    int lc[4];
#pragma unroll
    for (int pj = 0; pj < 4; ++pj) lc[pj] = lab[j0 + jb + pj * 16 + l16];

    f32x4 acc[2][4] = {};
#pragma unroll
    for (int ks = 0; ks < 4; ++ks) {
      const int ch = ks * 2 + (quad >> 1);
      const int off = ((ch ^ sw) << 4) + ((quad & 1) << 3);
      long bf[4];
#pragma unroll
      for (int p = 0; p < 4; ++p)
        bf[p] = *(const long*)&Bs[jp][p * 16 + l16][off];
#pragma unroll
      for (int pi = 0; pi < 2; ++pi)
#pragma unroll
        for (int pj = 0; pj < 4; ++pj)
          acc[pi][pj] = __builtin_amdgcn_mfma_f32_16x16x32_fp8_fp8(
              af[ks][pi], bf[pj], acc[pi][pj], 0, 0, 0);
    }

    float tcol[4] = {}, pcol[4] = {};
    if (offdiag) {
#pragma unroll
      for (int pi = 0; pi < 2; ++pi)
#pragma unroll
        for (int pj = 0; pj < 4; ++pj)
#pragma unroll
          for (int r = 0; r < 4; ++r) {
            const float s2 = acc[pi][pj][r];
            const float e = exp2f(s2);
            const bool match = (lr[pi][r] == lc[pj]);
            trow[pi][r] += e;
            tcol[pj] += e;
            pr[pi][r] += match ? e : 0.f;
            pcol[pj] += match ? e : 0.f;
            sacc += match ? s2 : 0.f;  // doubled at store (mirror pairs)
          }
      // fold this phase's col sums: reduce across quads, stage in LDS
#pragma unroll
      for (int pj = 0; pj < 4; ++pj) {
        float v = tcol[pj], q = pcol[pj];
        v += __shfl_xor(v, 16);
        q += __shfl_xor(q, 16);
        v += __shfl_xor(v, 32);
        q += __shfl_xor(q, 32);
        if (quad == 0) {
          atomicAdd(&tcolS[jb + pj * 16 + l16], v);  // LDS atomic, 4 waves
          atomicAdd(&pcolS[jb + pj * 16 + l16], q);
        }
      }
    } else {
#pragma unroll
      for (int pi = 0; pi < 2; ++pi)
#pragma unroll
        for (int pj = 0; pj < 4; ++pj)
#pragma unroll
          for (int r = 0; r < 4; ++r) {
            const float s2 = acc[pi][pj][r];
            const float e = exp2f(s2);
            const int rowl = rbase + pi * 16 + quad * 4 + r;
            const bool self = rowl == (jb + pj * 16 + l16);
            const bool match = (lr[pi][r] == lc[pj]) && !self;
            trow[pi][r] += self ? 0.f : e;
            pr[pi][r] += match ? e : 0.f;
            sacc += match ? s2 : 0.f;
          }
    }
  }

  // ---- row-side flush: reduce over 16 col-lanes, write-once slot bj ----
#pragma unroll
  for (int pi = 0; pi < 2; ++pi)
#pragma unroll
    for (int r = 0; r < 4; ++r) {
      float v = trow[pi][r], q = pr[pi][r];
      v += __shfl_xor(v, 1);
      q += __shfl_xor(q, 1);
      v += __shfl_xor(v, 2);
      q += __shfl_xor(q, 2);
      v += __shfl_xor(v, 4);
      q += __shfl_xor(q, 4);
      v += __shfl_xor(v, 8);
      q += __shfl_xor(q, 8);
      if (l16 == 0) {
        const int row = rbase + pi * 16 + quad * 4 + r;
        P[(size_t)bj * N + i0 + row] = v;
        Q[(size_t)bj * N + i0 + row] = q;
      }
    }
#pragma unroll
  for (int m = 1; m < 64; m <<= 1) sacc += __shfl_xor(sacc, m);
  if (lane == 0) sS[w] = sacc;
  __syncthreads();  // col partials + sS complete

  // ---- col-side flush (offdiag only): write-once slot bi ----
  if (offdiag && t < 128) {
    P[(size_t)bi * N + j0 + t] = tcolS[t];
    Q[(size_t)bi * N + j0 + t] = pcolS[t];
  }
  if (t == 0) {
    const float tot = sS[0] + sS[1] + sS[2] + sS[3];
    S[b] = tot * 0.69314718056f * (offdiag ? 2.f : 1.f);  // *ln2, mirror x2
  }
}

// ---------------------------------------------------------------------------
// Kernel 3: parallel finalize — 32 blocks x 256 thr, 256 rows each.
// LDS label histogram, fold 64 slot-partials per row, subtract S-slice
// (global thread g owns S[g], g<2080), one device atomic per block.
__global__ __launch_bounds__(256) void finalize_kernel(
    const int* __restrict__ lab, const float* __restrict__ P,
    const float* __restrict__ Q, const float* __restrict__ S,
    float* __restrict__ out, int N, int nS) {
  __shared__ int hist[256];
  __shared__ float red[4];
  const int b = blockIdx.x, t = threadIdx.x;
  const int lane = t & 63, w = t >> 6;
  hist[t] = 0;
  __syncthreads();
  for (int i = t; i < N; i += 256) atomicAdd(&hist[lab[i] & 255], 1);
  __syncthreads();

  const int i = b * 256 + t;
  float tot = 0.f, p = 0.f;
#pragma unroll 16
  for (int cc = 0; cc < 64; ++cc) {
    tot += P[(size_t)cc * N + i];
    p += Q[(size_t)cc * N + i];
  }
  const float u = tot - p;
  const float cnti = (float)(hist[lab[i] & 255] - 1);
  float local = cnti * __logf(u) + p / u;
  if (i < nS) local -= S[i];  // fold S (2080 entries over 8192 threads)
#pragma unroll
  for (int m = 1; m < 64; m <<= 1) local += __shfl_xor(local, m);
  if (lane == 0) red[w] = local;
  __syncthreads();
  if (t == 0) {
    float np = 0.f;
    for (int k = 0; k < 256; ++k) {
      const float m = (float)hist[k];
      np += m * m;
    }
    atomicAdd(out, (red[0] + red[1] + red[2] + red[3]) / (np - (float)N));
  }
}

// ---------------------------------------------------------------------------
extern "C" void kernel_launch(void* const* d_in, const int* in_sizes, int n_in,
                              void* d_out, int out_size, void* d_ws,
                              size_t ws_size, hipStream_t stream) {
  const float* X = (const float*)d_in[0];
  const int* lab = (const int*)d_in[1];
  float* out = (float*)d_out;

  const int N = in_sizes[1];  // 8192; D fixed at 128

  // workspace: Y8 (1MB) | P[64][N] (2MB) | Q[64][N] (2MB) | S[2080]
  unsigned char* Y8 = (unsigned char*)d_ws;
  float* P = (float*)(Y8 + (size_t)N * 128);
  float* Q = P + 64 * (size_t)N;
  float* S = Q + 64 * (size_t)N;

  // sqrt(log2e / T): MFMA outputs s*log2e so the epilogue is raw exp2
  const float scaleAB = 2.68579102f;  // sqrt(1.44269504 / 0.2)

  norm_kernel<<<N / 8, 256, 0, stream>>>(X, Y8, out, scaleAB);

  const int nt = N / 128;              // 64 tile-panels
  const int nblk = nt * (nt + 1) / 2;  // 2080 upper-tri tile pairs
  pass1_kernel<<<nblk, 256, 0, stream>>>(Y8, lab, P, Q, S, nt, N);
  finalize_kernel<<<32, 256, 0, stream>>>(lab, P, Q, S, out, N, nblk);
}

// Round 11
// 98.591 us; speedup vs baseline: 1.0207x; 1.0207x over previous
//
#include <hip/hip_runtime.h>
#include <math.h>

typedef float f32x4 __attribute__((ext_vector_type(4)));
typedef __attribute__((address_space(3))) unsigned int lds_u32;
typedef __attribute__((address_space(1))) const unsigned int glb_u32;

// ---------------------------------------------------------------------------
// R31: counted-vmcnt pipelined staging (catalog T3/T4) on the R24 structure.
//
// Evidence: steady pass1 ~37-45us across EVERY LDS-staged variant while the
// issue floor is ~15us; falsified as causes: occupancy (4/CU=6/CU=8/CU),
// barrier count (2 vs 8), total work (R30 triangular halved it - flat),
// global atomics (R23), LDS itself (R27 worse). Remaining consistent
// hypothesis: every __syncthreads drains vmcnt to 0, exposing full
// concurrency-loaded L2/L3 latency once per staging step. Fix (never tried
// here): NEVER drain in the loop -- triple-buffered tiles issued 3 ahead,
// counted s_waitcnt vmcnt(4) + raw s_barrier (no __syncthreads inside).
// Per-wave vmem in the loop = exactly 2 global_load_lds per tile, so the
// counts are exact: waits 4,4,4,4,4,4,2,0 across the 8 unrolled tiles.
// Column labels pre-staged to LDS (no other vmem in loop). sched_barrier(0)
// after each asm barrier per rule #18. exp2 scale-folding kept.
// ---------------------------------------------------------------------------

// Kernel 1: row normalization -> fp8 e4m3 rows PRE-SWIZZLED (16B chunk c of
// row r stored at chunk c ^ (r&7)). Zeroes out[0].
__global__ __launch_bounds__(256) void norm_kernel(
    const float* __restrict__ X, unsigned char* __restrict__ Y8,
    float* __restrict__ out, float scaleAB) {
  int t = threadIdx.x;
  int row = blockIdx.x * 8 + (t >> 5);
  int l32 = t & 31;
  float4 v = ((const float4*)(X + (size_t)row * 128))[l32];
  float s = v.x * v.x + v.y * v.y + v.z * v.z + v.w * v.w;
  s += __shfl_xor(s, 1);
  s += __shfl_xor(s, 2);
  s += __shfl_xor(s, 4);
  s += __shfl_xor(s, 8);
  s += __shfl_xor(s, 16);
  float inv = scaleAB * rsqrtf(fmaxf(s, 1e-24f));
  int pk = __builtin_amdgcn_cvt_pk_fp8_f32(v.x * inv, v.y * inv, 0, false);
  pk = __builtin_amdgcn_cvt_pk_fp8_f32(v.z * inv, v.w * inv, pk, true);
  int chunk = l32 >> 2;
  int off = ((chunk ^ (row & 7)) << 4) + ((l32 & 3) << 2);
  *(unsigned int*)(Y8 + (size_t)row * 128 + off) = (unsigned)pk;
  if (blockIdx.x == 0 && t == 0) out[0] = 0.f;
}

// ---------------------------------------------------------------------------
// Kernel 2: similarity pass, 64 panels x 16 chunks = 1024 blocks x 256 thr.
// Block (bi,c): rows [bi*128,+128) x cols [c*512,+512) in 8 tiles of 64
// cols, 3-deep pipelined staging, zero vmcnt drains in the loop.
__global__ __launch_bounds__(256, 4) void pass1_kernel(
    const unsigned char* __restrict__ Y8, const int* __restrict__ lab,
    float* __restrict__ P, float* __restrict__ Q, float* __restrict__ S,
    int N) {
  __shared__ unsigned char Bs[3][64][128];  // 24.6KB triple buffer
  __shared__ int labC[512];
  __shared__ float sS[4];

  const int b = blockIdx.x;
  const int bi = b >> 4, c = b & 15;
  const int i0 = bi * 128;
  const int j0 = c * 512;
  const int t = threadIdx.x;
  const int w = t >> 6, lane = t & 63;
  const int quad = lane >> 4, l16 = lane & 15;
  const int rbase = w * 32;  // wave owns rows [rbase, rbase+32)
  const int sw = l16 & 7;

  // ---- prologue (all vmem here is drained by the one __syncthreads) ----
  labC[t] = lab[j0 + t];
  labC[t + 256] = lab[j0 + 256 + t];

  long af[4][2];  // A fragments: one-time swizzled gathers (L2/L3-hot)
#pragma unroll
  for (int ks = 0; ks < 4; ++ks) {
    const int ch = ks * 2 + (quad >> 1);
    const int off = ((ch ^ sw) << 4) + ((quad & 1) << 3);
#pragma unroll
    for (int p = 0; p < 2; ++p)
      af[ks][p] =
          *(const long*)(Y8 + (size_t)(i0 + rbase + p * 16 + l16) * 128 + off);
  }
  int lr[2][4];
#pragma unroll
  for (int pi = 0; pi < 2; ++pi)
#pragma unroll
    for (int r = 0; r < 4; ++r)
      lr[pi][r] = lab[i0 + rbase + pi * 16 + quad * 4 + r];

  __syncthreads();  // labC visible; vmcnt == 0 for ALL waves from here

  // ---- issue tiles 0,1,2 (2 global_load_lds per wave per tile) ----
#pragma unroll
  for (int pt = 0; pt < 3; ++pt) {
    const unsigned char* src = Y8 + (size_t)(j0 + pt * 64) * 128;
    unsigned char* dst = (unsigned char*)&Bs[pt][0][0];
#pragma unroll
    for (int k = 0; k < 2; ++k) {
      const int c0 = w * 64 + k * 256;  // wave-uniform 16B-chunk index
      const int cc = c0 + lane;
      __builtin_amdgcn_global_load_lds((glb_u32*)(src + (size_t)cc * 16),
                                       (lds_u32*)(dst + c0 * 16), 16, 0, 0);
    }
  }

  float trow[2][4] = {};  // row exp-sums (self excluded on diag phase)
  float pr[2][4] = {};    // row positive exp-sums
  float sacc = 0.f;       // sum of s*log2e over positives (non-self)

#pragma unroll
  for (int jt = 0; jt < 8; ++jt) {
    const int buf = jt % 3;
    const int jt0 = j0 + jt * 64;
    const int rem = 7 - jt;  // tiles still outstanding beyond current

    // counted wait: current tile's loads done, next (up to 2) stay in flight
    if (rem >= 2)
      asm volatile("s_waitcnt vmcnt(4)" ::: "memory");
    else if (rem == 1)
      asm volatile("s_waitcnt vmcnt(2)" ::: "memory");
    else
      asm volatile("s_waitcnt vmcnt(0)" ::: "memory");
    asm volatile("s_barrier" ::: "memory");
    __builtin_amdgcn_sched_barrier(0);

    int lc[4];
#pragma unroll
    for (int pj = 0; pj < 4; ++pj) lc[pj] = labC[jt * 64 + pj * 16 + l16];

    f32x4 acc[2][4] = {};
#pragma unroll
    for (int ks = 0; ks < 4; ++ks) {
      const int ch = ks * 2 + (quad >> 1);
      const int off = ((ch ^ sw) << 4) + ((quad & 1) << 3);
      long bf[4];
#pragma unroll
      for (int p = 0; p < 4; ++p)
        bf[p] = *(const long*)&Bs[buf][p * 16 + l16][off];
#pragma unroll
      for (int pi = 0; pi < 2; ++pi)
#pragma unroll
        for (int pj = 0; pj < 4; ++pj)
          acc[pi][pj] = __builtin_amdgcn_mfma_f32_16x16x32_fp8_fp8(
              af[ks][pi], bf[pj], acc[pi][pj], 0, 0, 0);
    }

    // branch-free epilogue; e = exp2(s*log2e)
    const bool dphase = ((jt0 >> 7) == bi);  // wave-uniform
    if (dphase) {
#pragma unroll
      for (int pi = 0; pi < 2; ++pi)
#pragma unroll
        for (int pj = 0; pj < 4; ++pj)
#pragma unroll
          for (int r = 0; r < 4; ++r) {
            const float s2 = acc[pi][pj][r];
            const float e = exp2f(s2);
            const int rowl = rbase + pi * 16 + quad * 4 + r;
            const bool self = (i0 + rowl) == (jt0 + pj * 16 + l16);
            const bool match = (lr[pi][r] == lc[pj]) && !self;
            trow[pi][r] += self ? 0.f : e;
            pr[pi][r] += match ? e : 0.f;
            sacc += match ? s2 : 0.f;
          }
    } else {
#pragma unroll
      for (int pi = 0; pi < 2; ++pi)
#pragma unroll
        for (int pj = 0; pj < 4; ++pj)
#pragma unroll
          for (int r = 0; r < 4; ++r) {
            const float s2 = acc[pi][pj][r];
            const float e = exp2f(s2);
            const bool match = (lr[pi][r] == lc[pj]);
            trow[pi][r] += e;
            pr[pi][r] += match ? e : 0.f;
            sacc += match ? s2 : 0.f;
          }
    }

    // all waves done reading Bs[buf] -> safe to reissue into it
    __builtin_amdgcn_sched_barrier(0);
    asm volatile("s_barrier" ::: "memory");
    __builtin_amdgcn_sched_barrier(0);

    if (jt < 5) {  // issue tile jt+3 into the slot just freed
      const unsigned char* src = Y8 + (size_t)(jt0 + 192) * 128;
      unsigned char* dst = (unsigned char*)&Bs[buf][0][0];
#pragma unroll
      for (int k = 0; k < 2; ++k) {
        const int c0 = w * 64 + k * 256;
        const int cc = c0 + lane;
        __builtin_amdgcn_global_load_lds((glb_u32*)(src + (size_t)cc * 16),
                                         (lds_u32*)(dst + c0 * 16), 16, 0, 0);
      }
    }
  }

  // ---- flush: reduce across the 16 col-lanes, write-once partials ----
#pragma unroll
  for (int pi = 0; pi < 2; ++pi)
#pragma unroll
    for (int r = 0; r < 4; ++r) {
      float v = trow[pi][r], q = pr[pi][r];
      v += __shfl_xor(v, 1);
      q += __shfl_xor(q, 1);
      v += __shfl_xor(v, 2);
      q += __shfl_xor(q, 2);
      v += __shfl_xor(v, 4);
      q += __shfl_xor(q, 4);
      v += __shfl_xor(v, 8);
      q += __shfl_xor(q, 8);
      if (l16 == 0) {
        const int row = rbase + pi * 16 + quad * 4 + r;
        P[c * N + i0 + row] = v;  // (u + p) partial for this chunk
        Q[c * N + i0 + row] = q;  // p partial
      }
    }
#pragma unroll
  for (int m = 1; m < 64; m <<= 1) sacc += __shfl_xor(sacc, m);
  if (lane == 0) sS[w] = sacc;
  __syncthreads();
  if (t == 0)
    S[b] = (sS[0] + sS[1] + sS[2] + sS[3]) * 0.69314718056f;  // * ln2
}

// ---------------------------------------------------------------------------
// Kernel 3: parallel finalize — 32 blocks x 256 thr, 256 rows each.
// LDS label histogram, fold 16 chunk-partials per row, subtract this
// block's S-slice (32 of 1024), one device atomic per block into out[0].
__global__ __launch_bounds__(256) void finalize_kernel(
    const int* __restrict__ lab, const float* __restrict__ P,
    const float* __restrict__ Q, const float* __restrict__ S,
    float* __restrict__ out, int N) {
  __shared__ int hist[256];
  __shared__ float red[4];
  const int b = blockIdx.x, t = threadIdx.x;
  const int lane = t & 63, w = t >> 6;
  hist[t] = 0;
  __syncthreads();
  for (int i = t; i < N; i += 256) atomicAdd(&hist[lab[i] & 255], 1);
  __syncthreads();

  const int i = b * 256 + t;
  float tot = 0.f, p = 0.f;
#pragma unroll
  for (int cc = 0; cc < 16; ++cc) {
    tot += P[cc * N + i];
    p += Q[cc * N + i];
  }
  const float u = tot - p;
  const float cnti = (float)(hist[lab[i] & 255] - 1);
  float local = cnti * __logf(u) + p / u;
  if (t < 32) local -= S[b * 32 + t];  // fold this block's S-slice
#pragma unroll
  for (int m = 1; m < 64; m <<= 1) local += __shfl_xor(local, m);
  if (lane == 0) red[w] = local;
  __syncthreads();
  if (t == 0) {
    float np = 0.f;
    for (int k = 0; k < 256; ++k) {
      const float m = (float)hist[k];
      np += m * m;
    }
    atomicAdd(out, (red[0] + red[1] + red[2] + red[3]) / (np - (float)N));
  }
}

// ---------------------------------------------------------------------------
extern "C" void kernel_launch(void* const* d_in, const int* in_sizes, int n_in,
                              void* d_out, int out_size, void* d_ws,
                              size_t ws_size, hipStream_t stream) {
  const float* X = (const float*)d_in[0];
  const int* lab = (const int*)d_in[1];
  float* out = (float*)d_out;

  const int N = in_sizes[1];  // 8192; D fixed at 128

  // workspace: Y8 (1MB) | P[16][N] (512KB) | Q[16][N] (512KB) | S[1024]
  unsigned char* Y8 = (unsigned char*)d_ws;
  float* P = (float*)(Y8 + (size_t)N * 128);
  float* Q = P + 16 * (size_t)N;
  float* S = Q + 16 * (size_t)N;

  // sqrt(log2e / T): MFMA outputs s*log2e so the epilogue is raw exp2
  const float scaleAB = 2.68579102f;  // sqrt(1.44269504 / 0.2)

  norm_kernel<<<N / 8, 256, 0, stream>>>(X, Y8, out, scaleAB);

  const int nblk = (N / 128) * 16;  // 64 panels x 16 chunks = 1024
  pass1_kernel<<<nblk, 256, 0, stream>>>(Y8, lab, P, Q, S, N);
  finalize_kernel<<<32, 256, 0, stream>>>(lab, P, Q, S, out, N);
}